// Round 4
// baseline (194.083 us; speedup 1.0000x reference)
//
#include <hip/hip_runtime.h>
#include <hip/hip_cooperative_groups.h>

namespace cg = cooperative_groups;

// SLAYER SNN forward, MI355X. Round 17.
// vs R16: ENTIRE pipeline fused into ONE cooperative kernel (512 x 256,
//   2 blocks/CU co-resident, LDS union 60.8 KB). Phase A = wl1 fold (from
//   LDS-staged w1) + out zeroing (blocks 0..49) + R9 conv1 core per-wave,
//   4 frames/block x 4 passes -> u1 in ws. grid.sync(). Phase B = R16 kf
//   body (per-block wl2 fold -> wreg, scan1 -> f16 ls1h, conv2, register
//   scan2, parallel dense + atomicAdd). Removes k0 + two launch gaps, and
//   guarantees the fused kernel appears in rocprof top-5 with full counters
//   (everything was hidden below the 41 us workspace-fill cutoff).

#define DECAY 0.9048374180359595f   // exp(-1/10)

#define BAR_LGKM() asm volatile("s_waitcnt lgkmcnt(0)\n\ts_barrier" ::: "memory")
#define FENCE_LGKM() asm volatile("s_waitcnt lgkmcnt(0)" ::: "memory")

typedef __attribute__((ext_vector_type(8))) _Float16 half8;

__global__ __launch_bounds__(256, 2) void kall(
        const float* __restrict__ x,   const float* __restrict__ w1,
        const float* __restrict__ w2,  const float* __restrict__ lw,
        const float* __restrict__ wp1, const float* __restrict__ wp2,
        float* __restrict__ u1,        float* __restrict__ out) {
    // LDS union:
    //  phase A: [0,41472) xs 4x2592 f32 | [41472,43520) wl1 512 f32
    //           [43520,44320) w1 stage 200 f32
    //  phase B: [0,52800) ls1h 100x264 f16 | [52800,60800) ls2 100x20 f32
    __shared__ __align__(16) char smem[60800];
    float*    xs_all = (float*)smem;
    float*    wl1s   = (float*)(smem + 41472);
    float*    w1s    = (float*)(smem + 43520);
    _Float16* ls1h   = (_Float16*)smem;
    float*    ls2    = (float*)(smem + 52800);

    const int tid  = threadIdx.x;
    const int bid  = blockIdx.x;
    const int wave = tid >> 6, lane = tid & 63;
    const float a = DECAY;

    // ================= phase A: zero out, fold wl1, conv1+pool1 =================
    if (bid < 50) out[bid * 256 + tid] = 0.f;
    if (tid < 200) w1s[tid] = w1[tid];
    __syncthreads();
    {
        const float p1 = wp1[0];
        #pragma unroll
        for (int rep = 0; rep < 2; ++rep) {
            const int idx = rep * 256 + tid;
            const int f = idx & 7, c = (idx >> 3) & 3, e = (idx >> 5) & 7, cin = idx >> 8;
            const int cc = c * 2 + cin;
            int alo = e - 3; if (alo < 0) alo = 0;
            int ahi = e;     if (ahi > 4) ahi = 4;
            int blo = f - 3; if (blo < 0) blo = 0;
            int bhi = f;     if (bhi > 4) bhi = 4;
            float s = 0.f;
            for (int aa = alo; aa <= ahi; ++aa)
                for (int bb = blo; bb <= bhi; ++bb)
                    s += w1s[cc * 25 + aa * 5 + bb];
            wl1s[(cin * 8 + e) * 32 + c * 8 + f] = s * p1;
        }
    }
    __syncthreads();

    // per-wave R9 conv core, 4 passes (frames 0..6399)
    float* xs = xs_all + wave * 2592;
    #pragma unroll 1
    for (int pass = 0; pass < 4; ++pass) {
        const int frame = pass * 2048 + bid * 4 + wave;
        if (frame < 6400) {
            const int n = frame / 100, t = frame % 100;

            #pragma unroll
            for (int m0 = 0; m0 < 128; m0 += 64) {
                const int m = m0 + lane;
                if (m < 72) {
                    const int cin = m / 36, rem = m % 36;
                    const int rr = rem / 9, q4 = rem % 9;
                    const int pr = (rr == 0) ? 0 : (rr == 1) ? 9 : (rr == 2) ? 26 : 35;
                    *(float4*)(xs + cin * 1296 + pr * 36 + q4 * 4) =
                        make_float4(0.f, 0.f, 0.f, 0.f);
                }
            }
            #pragma unroll
            for (int m0 = 0; m0 < 192; m0 += 64) {
                const int m = m0 + lane;
                if (m < 144) {
                    const int cin = m / 72, rem = m % 72;
                    const int side = rem & 1, pr = rem >> 1;
                    *(float2*)(xs + cin * 1296 + pr * 36 + side * 34) =
                        make_float2(0.f, 0.f);
                }
            }
            const float4* xg = (const float4*)(x + (size_t)frame * 2048);
            #pragma unroll
            for (int q = 0; q < 8; ++q) {
                const int m = q * 64 + lane;
                const float4 v = xg[m];
                const int li = 4 * m;
                const int cin = li >> 10, row = (li >> 5) & 31, col = li & 31;
                const int r = row + 2;
                const int pr = (r & 3) * 9 + (r >> 2);
                float* d = xs + cin * 1296 + pr * 36 + col + 2;
                *(float2*)(d)     = make_float2(v.x, v.y);
                *(float2*)(d + 2) = make_float2(v.z, v.w);
            }
            FENCE_LGKM();

            const int cp = lane >> 5;
            const int i  = (lane >> 2) & 7;
            const int jh = (lane >> 1) & 1;
            const int eh = lane & 1;

            float acc[2][4] = {{0.f, 0.f, 0.f, 0.f}, {0.f, 0.f, 0.f, 0.f}};
            const float* tb = xs + (i + eh) * 36 + jh * 16;
            #pragma unroll
            for (int cin = 0; cin < 2; ++cin) {
                #pragma unroll
                for (int et = 0; et < 4; ++et) {
                    const int ro = cin * 1296 + et * 9 * 36;
                    float xr[20];
                    #pragma unroll
                    for (int b = 0; b < 5; ++b)
                        *(float4*)(xr + 4 * b) = *(const float4*)(tb + ro + 4 * b);
                    float wv[16];
                    const float* wp = wl1s + (cin * 8 + eh * 4 + et) * 32 + cp * 16;
                    #pragma unroll
                    for (int q = 0; q < 4; ++q)
                        *(float4*)(wv + 4 * q) = *(const float4*)(wp + 4 * q);
                    #pragma unroll
                    for (int cl = 0; cl < 2; ++cl) {
                        #pragma unroll
                        for (int jj = 0; jj < 4; ++jj) {
                            const int o = 4 * jj;
                            acc[cl][jj] += xr[o]*wv[cl*8]     + xr[o+1]*wv[cl*8+1]
                                         + xr[o+2]*wv[cl*8+2] + xr[o+3]*wv[cl*8+3]
                                         + xr[o+4]*wv[cl*8+4] + xr[o+5]*wv[cl*8+5]
                                         + xr[o+6]*wv[cl*8+6] + xr[o+7]*wv[cl*8+7];
                        }
                    }
                }
            }
            #pragma unroll
            for (int cl = 0; cl < 2; ++cl)
                #pragma unroll
                for (int jj = 0; jj < 4; ++jj)
                    acc[cl][jj] += __shfl_xor(acc[cl][jj], 1);

            const float o0 = eh ? acc[1][0] : acc[0][0];
            const float o1 = eh ? acc[1][1] : acc[0][1];
            const float o2 = eh ? acc[1][2] : acc[0][2];
            const float o3 = eh ? acc[1][3] : acc[0][3];
            *(float4*)(u1 + (size_t)t * 16384 + n * 256 + (2 * cp + eh) * 64 + i * 8 + jh * 4) =
                make_float4(o0, o1, o2, o3);
        }
    }

    cg::this_grid().sync();   // u1 complete + visible device-wide

    // ================= phase B: scan1 + conv2(oct) + scan2 + dense =================
    const int nB  = (bid & 7) * 8 + (bid >> 6);   // XCD-aware, bijective
    const int oct = (bid >> 3) & 7;               // c2 channel

    // fold wl2 (this block's channel) into ls2[0..63] scratch
    if (tid < 64) {
        const float p2 = wp2[0];
        const int cin = tid >> 4, e = (tid >> 2) & 3, f = tid & 3;
        int alo = e - 1; if (alo < 0) alo = 0;
        int ahi = e;     if (ahi > 2) ahi = 2;
        int blo = f - 1; if (blo < 0) blo = 0;
        int bhi = f;     if (bhi > 2) bhi = 2;
        float s = 0.f;
        for (int aa = alo; aa <= ahi; ++aa)
            for (int bb = blo; bb <= bhi; ++bb)
                s += w2[((oct * 4 + cin) * 3 + aa) * 3 + bb];
        ls2[cin * 16 + e * 4 + f] = s * p2;
    }
    __syncthreads();

    float4 wreg[16];   // [cin*4+e] = folded taps f0..3 for channel oct
    #pragma unroll
    for (int q = 0; q < 16; ++q)
        wreg[q] = *(const float4*)(ls2 + (q >> 2) * 16 + (q & 3) * 4);

    const float* up = u1 + nB * 256 + tid;

    // P2 mapping: thread = (sub, i2, jhp)
    const int sub = tid >> 3, l8 = tid & 7;
    const int i2 = l8 >> 1, jhp = l8 & 1;

    // --- P1: load all 100 u, scan1, publish f16 spikes ---
    float vbuf[100];
    #pragma unroll
    for (int k = 0; k < 100; ++k) vbuf[k] = up[(size_t)k * 16384];
    {
        float psp = 0.f, rr = 0.f;
        #pragma unroll
        for (int k = 0; k < 100; ++k) {
            psp = a * psp + vbuf[k];
            const float vv = psp - rr;
            const float s = (vv >= 1.f) ? 1.f : 0.f;
            rr = a * (rr + s);
            ls1h[k * 264 + tid] = (_Float16)s;   // 0/1 exact in f16
        }
    }
    BAR_LGKM();   // also drains wreg ds_reads before P2 overwrites ls2[0..63]

    // --- P2: conv2 (1 channel), 4 predicated passes x 32 slots ---
    #pragma unroll 1
    for (int pass = 0; pass < 4; ++pass) {
        const int slot = sub + 32 * pass;
        if (slot < 100) {
            const _Float16* sb = ls1h + slot * 264;
            float acc0 = 0.f, acc1 = 0.f;
            #pragma unroll
            for (int cin = 0; cin < 4; ++cin) {
                #pragma unroll
                for (int e = 0; e < 4; ++e) {
                    const int ri = 2 * i2 + e - 1;            // input row, -1..8
                    const int rc = (ri < 0) ? 0 : (ri > 7 ? 7 : ri);
                    const bool rok = (ri >= 0) && (ri <= 7);
                    const half8 hv = *(const half8*)(sb + cin * 64 + rc * 8);
                    float rr8[8];
                    #pragma unroll
                    for (int m = 0; m < 8; ++m) rr8[m] = (float)hv[m];
                    float xr[6];
                    xr[0] = jhp ? rr8[3] : 0.0f;
                    xr[1] = jhp ? rr8[4] : rr8[0];
                    xr[2] = jhp ? rr8[5] : rr8[1];
                    xr[3] = jhp ? rr8[6] : rr8[2];
                    xr[4] = jhp ? rr8[7] : rr8[3];
                    xr[5] = jhp ? 0.0f   : rr8[4];
                    if (!rok) {
                        #pragma unroll
                        for (int m = 0; m < 6; ++m) xr[m] = 0.0f;
                    }
                    const float4 wf = wreg[cin * 4 + e];
                    acc0 += xr[0] * wf.x; acc0 += xr[1] * wf.y;
                    acc0 += xr[2] * wf.z; acc0 += xr[3] * wf.w;
                    acc1 += xr[2] * wf.x; acc1 += xr[3] * wf.y;
                    acc1 += xr[4] * wf.z; acc1 += xr[5] * wf.w;
                }
            }
            *(float2*)(ls2 + slot * 20 + i2 * 4 + 2 * jhp) =
                make_float2(acc0, acc1);
        }
    }
    BAR_LGKM();

    // --- scan2: wave0 lanes 0..15 (one per cell), register-resident ---
    if (wave == 0 && (tid & 63) < 16) {
        const int cell = tid & 63;
        float ub[100];
        #pragma unroll
        for (int k = 0; k < 100; ++k) ub[k] = ls2[k * 20 + cell];
        float psp2 = 0.f, rr2 = 0.f;
        #pragma unroll
        for (int k = 0; k < 100; ++k) {
            psp2 = a * psp2 + ub[k];
            const float vv = psp2 - rr2;
            const float s = (vv >= 1.f) ? 1.f : 0.f;
            rr2 = a * (rr2 + s);
            ls2[k * 20 + cell] = s;     // store-only publish
        }
    }
    BAR_LGKM();

    // --- dense: thread (t,o) dots 16 spikes x 16 weights ---
    if (tid < 200) {
        const int t = tid >> 1, o = tid & 1;
        const float* srow = ls2 + t * 20;
        const float* wrow = lw + o * 128 + oct * 16;
        const float4 s0 = *(const float4*)(srow);
        const float4 s1 = *(const float4*)(srow + 4);
        const float4 s2 = *(const float4*)(srow + 8);
        const float4 s3 = *(const float4*)(srow + 12);
        const float4 w0 = *(const float4*)(wrow);
        const float4 w1v = *(const float4*)(wrow + 4);
        const float4 w2v = *(const float4*)(wrow + 8);
        const float4 w3 = *(const float4*)(wrow + 12);
        float v = 0.f;
        v += s0.x * w0.x;  v += s0.y * w0.y;  v += s0.z * w0.z;  v += s0.w * w0.w;
        v += s1.x * w1v.x; v += s1.y * w1v.y; v += s1.z * w1v.z; v += s1.w * w1v.w;
        v += s2.x * w2v.x; v += s2.y * w2v.y; v += s2.z * w2v.z; v += s2.w * w2v.w;
        v += s3.x * w3.x;  v += s3.y * w3.y;  v += s3.z * w3.z;  v += s3.w * w3.w;
        atomicAdd(&out[nB * 200 + t * 2 + o], v);
    }
}

extern "C" void kernel_launch(void* const* d_in, const int* in_sizes, int n_in,
                              void* d_out, int out_size, void* d_ws, size_t ws_size,
                              hipStream_t stream) {
    const float* x   = (const float*)d_in[0];
    const float* w1  = (const float*)d_in[1];
    const float* w2  = (const float*)d_in[2];
    const float* lw  = (const float*)d_in[3];
    const float* wp1 = (const float*)d_in[4];
    const float* wp2 = (const float*)d_in[5];

    float* u1  = (float*)d_ws;           // 1,638,400 floats
    float* out = (float*)d_out;          // (64,100,2) = 12800 floats

    void* args[] = { (void*)&x, (void*)&w1, (void*)&w2, (void*)&lw,
                     (void*)&wp1, (void*)&wp2, (void*)&u1, (void*)&out };
    hipLaunchCooperativeKernel((const void*)kall, dim3(512), dim3(256),
                               args, 0, stream);
}

// Round 5
// 129.288 us; speedup vs baseline: 1.5012x; 1.5012x over previous
//
#include <hip/hip_runtime.h>

// SLAYER SNN forward, MI355X. Round 18.
// vs R17 (cooperative fusion, 138.7 us alone -- REVERTED): back to the
//   measured-best R16 3-kernel structure, minus k0, plus u1 relayout.
// vs R16:
//   * k0 eliminated. k1 folds wl1 in-block (w1 staged to LDS, single-wave
//     fences) and blocks 0..49 zero `out`. kf folds wl2 in-block (R17 code).
//     Saves one dispatch + one inter-kernel gap.
//   * u1 relayout t-major -> n-major [n][t][256]. kf P1 now streams a
//     contiguous 102.4 KB slice per block (was 100 loads at 64 KB stride
//     spanning 6.4 MB of cross-XCD dirty lines). k1 write still 1 KB
//     contiguous per block. R17's counters (VALUBusy 10% on the fused
//     all-in-one) proved the pipeline is latency-bound, not pipe-bound.
// k1 conv core and kf phase B are byte-identical to R16 otherwise.

#define DECAY 0.9048374180359595f   // exp(-1/10)

#define BAR_LGKM() asm volatile("s_waitcnt lgkmcnt(0)\n\ts_barrier" ::: "memory")
#define FENCE_LGKM() asm volatile("s_waitcnt lgkmcnt(0)" ::: "memory")

typedef __attribute__((ext_vector_type(8))) _Float16 half8;

// ---------------- k1: conv1+pool1 (R9 core) + in-block wl1 fold + out zero ----------------
__global__ __launch_bounds__(64) void k1(const float* __restrict__ x,
        const float* __restrict__ w1, const float* __restrict__ wp1,
        float* __restrict__ u1, float* __restrict__ out) {
    __shared__ __align__(16) float xs[2 * 1296];
    __shared__ __align__(16) float wl[512];
    __shared__ __align__(16) float w1s[200];
    const int lane = threadIdx.x;
    const int frame = blockIdx.x;                  // = n*100 + t (x is n-major)
    const int n = frame / 100, t = frame % 100;

    // zero out (blocks 0..49 cover 12800 floats)
    if (frame < 50) {
        #pragma unroll
        for (int q = 0; q < 4; ++q)
            out[frame * 256 + q * 64 + lane] = 0.f;
    }

    // stage w1 -> LDS (200 floats)
    #pragma unroll
    for (int q = 0; q < 4; ++q) {
        const int m = q * 64 + lane;
        if (m < 200) w1s[m] = w1[m];
    }
    FENCE_LGKM();   // single-wave block: lgkm fence orders LDS writes/reads

    // fold wl1 in-block: wl[(cin*8+e)*32 + c*8 + f]
    {
        const float p1 = wp1[0];
        #pragma unroll
        for (int rep = 0; rep < 8; ++rep) {
            const int idx = rep * 64 + lane;
            const int f = idx & 7, c = (idx >> 3) & 3, e = (idx >> 5) & 7, cin = idx >> 8;
            const int cc = c * 2 + cin;
            int alo = e - 3; if (alo < 0) alo = 0;
            int ahi = e;     if (ahi > 4) ahi = 4;
            int blo = f - 3; if (blo < 0) blo = 0;
            int bhi = f;     if (bhi > 4) bhi = 4;
            float s = 0.f;
            for (int aa = alo; aa <= ahi; ++aa)
                for (int bb = blo; bb <= bhi; ++bb)
                    s += w1s[cc * 25 + aa * 5 + bb];
            wl[(cin * 8 + e) * 32 + c * 8 + f] = s * p1;
        }
    }
    FENCE_LGKM();

    // stage x frame -> xs (padded 36x36, pr-permuted rows)
    #pragma unroll
    for (int m0 = 0; m0 < 128; m0 += 64) {
        const int m = m0 + lane;
        if (m < 72) {
            const int cin = m / 36, rem = m % 36;
            const int rr = rem / 9, q4 = rem % 9;
            const int pr = (rr == 0) ? 0 : (rr == 1) ? 9 : (rr == 2) ? 26 : 35;
            *(float4*)(xs + cin * 1296 + pr * 36 + q4 * 4) = make_float4(0.f, 0.f, 0.f, 0.f);
        }
    }
    #pragma unroll
    for (int m0 = 0; m0 < 192; m0 += 64) {
        const int m = m0 + lane;
        if (m < 144) {
            const int cin = m / 72, rem = m % 72;
            const int side = rem & 1, pr = rem >> 1;
            *(float2*)(xs + cin * 1296 + pr * 36 + side * 34) = make_float2(0.f, 0.f);
        }
    }
    const float4* xg = (const float4*)(x + (size_t)frame * 2048);
    #pragma unroll
    for (int q = 0; q < 8; ++q) {
        const int m = q * 64 + lane;
        const float4 v = xg[m];
        const int li = 4 * m;
        const int cin = li >> 10, row = (li >> 5) & 31, col = li & 31;
        const int r = row + 2;
        const int pr = (r & 3) * 9 + (r >> 2);
        float* d = xs + cin * 1296 + pr * 36 + col + 2;
        *(float2*)(d)     = make_float2(v.x, v.y);
        *(float2*)(d + 2) = make_float2(v.z, v.w);
    }
    FENCE_LGKM();

    const int cp = lane >> 5;
    const int i  = (lane >> 2) & 7;
    const int jh = (lane >> 1) & 1;
    const int eh = lane & 1;

    float acc[2][4] = {{0.f, 0.f, 0.f, 0.f}, {0.f, 0.f, 0.f, 0.f}};
    const float* tb = xs + (i + eh) * 36 + jh * 16;
    #pragma unroll
    for (int cin = 0; cin < 2; ++cin) {
        #pragma unroll
        for (int et = 0; et < 4; ++et) {
            const int ro = cin * 1296 + et * 9 * 36;
            float xr[20];
            #pragma unroll
            for (int b = 0; b < 5; ++b)
                *(float4*)(xr + 4 * b) = *(const float4*)(tb + ro + 4 * b);
            float wv[16];
            const float* wp = wl + (cin * 8 + eh * 4 + et) * 32 + cp * 16;
            #pragma unroll
            for (int q = 0; q < 4; ++q)
                *(float4*)(wv + 4 * q) = *(const float4*)(wp + 4 * q);
            #pragma unroll
            for (int cl = 0; cl < 2; ++cl) {
                #pragma unroll
                for (int jj = 0; jj < 4; ++jj) {
                    const int o = 4 * jj;
                    acc[cl][jj] += xr[o]*wv[cl*8]     + xr[o+1]*wv[cl*8+1]
                                 + xr[o+2]*wv[cl*8+2] + xr[o+3]*wv[cl*8+3]
                                 + xr[o+4]*wv[cl*8+4] + xr[o+5]*wv[cl*8+5]
                                 + xr[o+6]*wv[cl*8+6] + xr[o+7]*wv[cl*8+7];
                }
            }
        }
    }
    #pragma unroll
    for (int cl = 0; cl < 2; ++cl)
        #pragma unroll
        for (int jj = 0; jj < 4; ++jj)
            acc[cl][jj] += __shfl_xor(acc[cl][jj], 1);

    const float o0 = eh ? acc[1][0] : acc[0][0];
    const float o1 = eh ? acc[1][1] : acc[0][1];
    const float o2 = eh ? acc[1][2] : acc[0][2];
    const float o3 = eh ? acc[1][3] : acc[0][3];
    // n-major u1: [n][t][256]
    *(float4*)(u1 + (size_t)n * 25600 + t * 256 + (2 * cp + eh) * 64 + i * 8 + jh * 4) =
        make_float4(o0, o1, o2, o3);
}

// ---------------- kf: fused scan1 + conv2(oct) + scan2 + dense ----------------
// grid 512 x 256: oct = (bid>>3)&7, n = (bid&7)*8 + (bid>>6)  (bijective;
// the 8 oct siblings of each n share bid%8 -> one XCD's L2 for the u1 slice).
// ls1h: 100 slots x 264 halfs (52.8 KB). ls2: 100 x 20 floats (8 KB);
// ls2[0..63] doubles as wl2-fold scratch before P2 overwrites it.
__global__ __launch_bounds__(256, 2) void kf(const float* __restrict__ u1,
        const float* __restrict__ w2, const float* __restrict__ wp2,
        const float* __restrict__ lw, float* __restrict__ out) {
    __shared__ __align__(16) _Float16 ls1h[100 * 264];  // 52.8 KB
    __shared__ __align__(16) float    ls2[100 * 20];    //  8.0 KB
    const int tid = threadIdx.x;
    const int bid = blockIdx.x;
    const int n   = (bid & 7) * 8 + (bid >> 6);   // XCD-aware, bijective
    const int oct = (bid >> 3) & 7;               // c2 channel
    const int wave = tid >> 6;
    const float a = DECAY;

    // fold wl2 (this block's channel) into ls2[0..63] scratch
    if (tid < 64) {
        const float p2 = wp2[0];
        const int cin = tid >> 4, e = (tid >> 2) & 3, f = tid & 3;
        int alo = e - 1; if (alo < 0) alo = 0;
        int ahi = e;     if (ahi > 2) ahi = 2;
        int blo = f - 1; if (blo < 0) blo = 0;
        int bhi = f;     if (bhi > 2) bhi = 2;
        float s = 0.f;
        for (int aa = alo; aa <= ahi; ++aa)
            for (int bb = blo; bb <= bhi; ++bb)
                s += w2[((oct * 4 + cin) * 3 + aa) * 3 + bb];
        ls2[cin * 16 + e * 4 + f] = s * p2;
    }
    __syncthreads();

    float4 wreg[16];   // [cin*4+e] = folded taps f0..3 for channel oct
    #pragma unroll
    for (int q = 0; q < 16; ++q)
        wreg[q] = *(const float4*)(ls2 + (q >> 2) * 16 + (q & 3) * 4);

    // n-major u1: contiguous 102.4 KB per block
    const float* up = u1 + (size_t)n * 25600 + tid;

    // P2 mapping: thread = (sub, i2, jhp)
    const int sub = tid >> 3, l8 = tid & 7;
    const int i2 = l8 >> 1, jhp = l8 & 1;

    // --- P1: load all 100 u, scan1, publish f16 spikes ---
    float vbuf[100];
    #pragma unroll
    for (int k = 0; k < 100; ++k) vbuf[k] = up[k * 256];
    {
        float psp = 0.f, rr = 0.f;
        #pragma unroll
        for (int k = 0; k < 100; ++k) {
            psp = a * psp + vbuf[k];
            const float vv = psp - rr;
            const float s = (vv >= 1.f) ? 1.f : 0.f;
            rr = a * (rr + s);
            ls1h[k * 264 + tid] = (_Float16)s;   // 0/1 exact in f16
        }
    }
    BAR_LGKM();   // orders wreg ds_reads before P2 overwrites ls2[0..63]

    // --- P2: conv2 (1 channel), 4 predicated passes x 32 slots ---
    #pragma unroll 1
    for (int pass = 0; pass < 4; ++pass) {
        const int slot = sub + 32 * pass;
        if (slot < 100) {
            const _Float16* sb = ls1h + slot * 264;
            float acc0 = 0.f, acc1 = 0.f;
            #pragma unroll
            for (int cin = 0; cin < 4; ++cin) {
                #pragma unroll
                for (int e = 0; e < 4; ++e) {
                    const int ri = 2 * i2 + e - 1;            // input row, -1..8
                    const int rc = (ri < 0) ? 0 : (ri > 7 ? 7 : ri);
                    const bool rok = (ri >= 0) && (ri <= 7);
                    const half8 hv = *(const half8*)(sb + cin * 64 + rc * 8);
                    float rr8[8];
                    #pragma unroll
                    for (int m = 0; m < 8; ++m) rr8[m] = (float)hv[m];
                    float xr[6];
                    xr[0] = jhp ? rr8[3] : 0.0f;
                    xr[1] = jhp ? rr8[4] : rr8[0];
                    xr[2] = jhp ? rr8[5] : rr8[1];
                    xr[3] = jhp ? rr8[6] : rr8[2];
                    xr[4] = jhp ? rr8[7] : rr8[3];
                    xr[5] = jhp ? 0.0f   : rr8[4];
                    if (!rok) {
                        #pragma unroll
                        for (int m = 0; m < 6; ++m) xr[m] = 0.0f;
                    }
                    const float4 wf = wreg[cin * 4 + e];
                    acc0 += xr[0] * wf.x; acc0 += xr[1] * wf.y;
                    acc0 += xr[2] * wf.z; acc0 += xr[3] * wf.w;
                    acc1 += xr[2] * wf.x; acc1 += xr[3] * wf.y;
                    acc1 += xr[4] * wf.z; acc1 += xr[5] * wf.w;
                }
            }
            *(float2*)(ls2 + slot * 20 + i2 * 4 + 2 * jhp) =
                make_float2(acc0, acc1);
        }
    }
    BAR_LGKM();

    // --- scan2: wave0 lanes 0..15 (one per cell), register-resident ---
    if (wave == 0 && (tid & 63) < 16) {
        const int cell = tid & 63;
        float ub[100];
        #pragma unroll
        for (int k = 0; k < 100; ++k) ub[k] = ls2[k * 20 + cell];
        float psp2 = 0.f, rr2 = 0.f;
        #pragma unroll
        for (int k = 0; k < 100; ++k) {
            psp2 = a * psp2 + ub[k];
            const float vv = psp2 - rr2;
            const float s = (vv >= 1.f) ? 1.f : 0.f;
            rr2 = a * (rr2 + s);
            ls2[k * 20 + cell] = s;     // store-only publish
        }
    }
    BAR_LGKM();

    // --- dense: thread (t,o) dots 16 spikes x 16 weights ---
    if (tid < 200) {
        const int t = tid >> 1, o = tid & 1;
        const float* srow = ls2 + t * 20;
        const float* wrow = lw + o * 128 + oct * 16;
        const float4 s0 = *(const float4*)(srow);
        const float4 s1 = *(const float4*)(srow + 4);
        const float4 s2 = *(const float4*)(srow + 8);
        const float4 s3 = *(const float4*)(srow + 12);
        const float4 w0 = *(const float4*)(wrow);
        const float4 w1v = *(const float4*)(wrow + 4);
        const float4 w2v = *(const float4*)(wrow + 8);
        const float4 w3 = *(const float4*)(wrow + 12);
        float v = 0.f;
        v += s0.x * w0.x;  v += s0.y * w0.y;  v += s0.z * w0.z;  v += s0.w * w0.w;
        v += s1.x * w1v.x; v += s1.y * w1v.y; v += s1.z * w1v.z; v += s1.w * w1v.w;
        v += s2.x * w2v.x; v += s2.y * w2v.y; v += s2.z * w2v.z; v += s2.w * w2v.w;
        v += s3.x * w3.x;  v += s3.y * w3.y;  v += s3.z * w3.z;  v += s3.w * w3.w;
        atomicAdd(&out[n * 200 + t * 2 + o], v);
    }
}

extern "C" void kernel_launch(void* const* d_in, const int* in_sizes, int n_in,
                              void* d_out, int out_size, void* d_ws, size_t ws_size,
                              hipStream_t stream) {
    const float* x   = (const float*)d_in[0];
    const float* w1  = (const float*)d_in[1];
    const float* w2  = (const float*)d_in[2];
    const float* lw  = (const float*)d_in[3];
    const float* wp1 = (const float*)d_in[4];
    const float* wp2 = (const float*)d_in[5];

    float* u1  = (float*)d_ws;           // 1,638,400 floats, n-major [n][t][256]
    float* out = (float*)d_out;          // (64,100,2) = 12800 floats

    k1<<<6400, 64, 0, stream>>>(x, w1, wp1, u1, out);
    kf<<<512, 256, 0, stream>>>(u1, w2, wp2, lw, out);
}

// Round 6
// 126.909 us; speedup vs baseline: 1.5293x; 1.0187x over previous
//
#include <hip/hip_runtime.h>

// SLAYER SNN forward, MI355X. Round 19.
// Accounting via R17's calibration (dur = 42us fill + kernels + ~13us floor):
//   kf has been ~40-50us every round regardless of P2/tail changes; R13's
//   direct counters showed it fetch-bound at 287 GB/s effective. Root cause:
//   P1's 100 per-thread loads batched by register pressure (vbuf[100] +
//   wreg[64] vs 128 VGPRs) and scan1 duplicated x8 oct-siblings.
// vs R18:
//   * NEW k_s (64 blocks x 256 thr, no LDS): per-n scan1. v[100] loads issue
//     back-to-back (no competing regs), scan ONCE per n, publish spikes f16
//     in the padded [t][264] layout kf's LDS wants. 0/1 exact in f16.
//   * kf: P1 replaced by a 52.8 KB bulk copy (13 coalesced float4/thread ->
//     ds_write). No scan, no cvt, no vbuf. wl2 fold scratch moved to
//     ls2[2000..2063] (never overwritten -> wreg loads after the one barrier).
//   * k0 back (4 blocks x 128, wl1 fold only) -- R18's per-block fold ran
//     6400x. k1 = R16 core, n-major u1 write, keeps out-zeroing.

#define DECAY 0.9048374180359595f   // exp(-1/10)

#define BAR_LGKM() asm volatile("s_waitcnt lgkmcnt(0)\n\ts_barrier" ::: "memory")
#define FENCE_LGKM() asm volatile("s_waitcnt lgkmcnt(0)" ::: "memory")

typedef __attribute__((ext_vector_type(8))) _Float16 half8;

// ---------------- k0: fold wl1 (512 entries, 4 blocks x 128) ----------------
__global__ __launch_bounds__(128) void k0_fold(const float* __restrict__ w1,
        const float* __restrict__ wp1, float* __restrict__ wl1) {
    const int idx = blockIdx.x * 128 + threadIdx.x;   // 0..511
    const float p1 = wp1[0];
    const int f = idx & 7, c = (idx >> 3) & 3, e = (idx >> 5) & 7, cin = idx >> 8;
    const int cc = c * 2 + cin;
    int alo = e - 3; if (alo < 0) alo = 0;
    int ahi = e;     if (ahi > 4) ahi = 4;
    int blo = f - 3; if (blo < 0) blo = 0;
    int bhi = f;     if (bhi > 4) bhi = 4;
    float s = 0.f;
    for (int a = alo; a <= ahi; ++a)
        for (int b = blo; b <= bhi; ++b)
            s += w1[cc * 25 + a * 5 + b];
    wl1[(cin * 8 + e) * 32 + c * 8 + f] = s * p1;
}

// ---------------- k1: conv1+pool1 (R9 core) + out zero, n-major u1 ----------------
__global__ __launch_bounds__(64) void k1(const float* __restrict__ x,
        const float* __restrict__ wg, float* __restrict__ u1,
        float* __restrict__ out) {
    __shared__ __align__(16) float xs[2 * 1296];
    __shared__ __align__(16) float wl[512];
    const int lane = threadIdx.x;
    const int frame = blockIdx.x;                  // = n*100 + t (x is n-major)
    const int n = frame / 100, t = frame % 100;

    // zero out (blocks 0..49 cover 12800 floats)
    if (frame < 50) {
        #pragma unroll
        for (int q = 0; q < 4; ++q)
            out[frame * 256 + q * 64 + lane] = 0.f;
    }

    *(float4*)(wl + 4 * lane)       = *(const float4*)(wg + 4 * lane);
    *(float4*)(wl + 256 + 4 * lane) = *(const float4*)(wg + 256 + 4 * lane);

    #pragma unroll
    for (int m0 = 0; m0 < 128; m0 += 64) {
        const int m = m0 + lane;
        if (m < 72) {
            const int cin = m / 36, rem = m % 36;
            const int rr = rem / 9, q4 = rem % 9;
            const int pr = (rr == 0) ? 0 : (rr == 1) ? 9 : (rr == 2) ? 26 : 35;
            *(float4*)(xs + cin * 1296 + pr * 36 + q4 * 4) = make_float4(0.f, 0.f, 0.f, 0.f);
        }
    }
    #pragma unroll
    for (int m0 = 0; m0 < 192; m0 += 64) {
        const int m = m0 + lane;
        if (m < 144) {
            const int cin = m / 72, rem = m % 72;
            const int side = rem & 1, pr = rem >> 1;
            *(float2*)(xs + cin * 1296 + pr * 36 + side * 34) = make_float2(0.f, 0.f);
        }
    }
    const float4* xg = (const float4*)(x + (size_t)frame * 2048);
    #pragma unroll
    for (int q = 0; q < 8; ++q) {
        const int m = q * 64 + lane;
        const float4 v = xg[m];
        const int li = 4 * m;
        const int cin = li >> 10, row = (li >> 5) & 31, col = li & 31;
        const int r = row + 2;
        const int pr = (r & 3) * 9 + (r >> 2);
        float* d = xs + cin * 1296 + pr * 36 + col + 2;
        *(float2*)(d)     = make_float2(v.x, v.y);
        *(float2*)(d + 2) = make_float2(v.z, v.w);
    }
    FENCE_LGKM();

    const int cp = lane >> 5;
    const int i  = (lane >> 2) & 7;
    const int jh = (lane >> 1) & 1;
    const int eh = lane & 1;

    float acc[2][4] = {{0.f, 0.f, 0.f, 0.f}, {0.f, 0.f, 0.f, 0.f}};
    const float* tb = xs + (i + eh) * 36 + jh * 16;
    #pragma unroll
    for (int cin = 0; cin < 2; ++cin) {
        #pragma unroll
        for (int et = 0; et < 4; ++et) {
            const int ro = cin * 1296 + et * 9 * 36;
            float xr[20];
            #pragma unroll
            for (int b = 0; b < 5; ++b)
                *(float4*)(xr + 4 * b) = *(const float4*)(tb + ro + 4 * b);
            float wv[16];
            const float* wp = wl + (cin * 8 + eh * 4 + et) * 32 + cp * 16;
            #pragma unroll
            for (int q = 0; q < 4; ++q)
                *(float4*)(wv + 4 * q) = *(const float4*)(wp + 4 * q);
            #pragma unroll
            for (int cl = 0; cl < 2; ++cl) {
                #pragma unroll
                for (int jj = 0; jj < 4; ++jj) {
                    const int o = 4 * jj;
                    acc[cl][jj] += xr[o]*wv[cl*8]     + xr[o+1]*wv[cl*8+1]
                                 + xr[o+2]*wv[cl*8+2] + xr[o+3]*wv[cl*8+3]
                                 + xr[o+4]*wv[cl*8+4] + xr[o+5]*wv[cl*8+5]
                                 + xr[o+6]*wv[cl*8+6] + xr[o+7]*wv[cl*8+7];
                }
            }
        }
    }
    #pragma unroll
    for (int cl = 0; cl < 2; ++cl)
        #pragma unroll
        for (int jj = 0; jj < 4; ++jj)
            acc[cl][jj] += __shfl_xor(acc[cl][jj], 1);

    const float o0 = eh ? acc[1][0] : acc[0][0];
    const float o1 = eh ? acc[1][1] : acc[0][1];
    const float o2 = eh ? acc[1][2] : acc[0][2];
    const float o3 = eh ? acc[1][3] : acc[0][3];
    // n-major u1: [n][t][256]
    *(float4*)(u1 + (size_t)n * 25600 + t * 256 + (2 * cp + eh) * 64 + i * 8 + jh * 4) =
        make_float4(o0, o1, o2, o3);
}

// ---------------- k_s: scan1 per n, publish f16 spikes [n][t*264+cell] ----------------
// 64 blocks x 256 threads, no LDS, no weight regs -> all 100 loads issue
// back-to-back (coalesced 1 KB per k). Scan runs ONCE per n (was x8 in kf).
__global__ __launch_bounds__(256) void k_s(const float* __restrict__ u1,
        _Float16* __restrict__ s1g) {
    const int n = blockIdx.x, tid = threadIdx.x;
    const float a = DECAY;
    const float* up = u1 + (size_t)n * 25600 + tid;
    _Float16* sp = s1g + (size_t)n * 26400 + tid;

    float v[100];
    #pragma unroll
    for (int k = 0; k < 100; ++k) v[k] = up[k * 256];

    float psp = 0.f, rr = 0.f;
    #pragma unroll
    for (int k = 0; k < 100; ++k) {
        psp = a * psp + v[k];
        const float vv = psp - rr;
        const float s = (vv >= 1.f) ? 1.f : 0.f;
        rr = a * (rr + s);
        sp[k * 264] = (_Float16)s;   // 0/1 exact in f16; pad halfs 256..263 unused
    }
}

// ---------------- kf: stream spikes + conv2(oct) + scan2 + dense ----------------
// grid 512 x 256: oct = (bid>>3)&7, n = (bid&7)*8 + (bid>>6)  (bijective;
// 8 oct siblings share bid%8 -> one XCD's L2 for the 52.8 KB spike slice).
// ls1h: 100 x 264 halfs (52.8 KB) bulk-copied from s1g (13 float4/thread).
// ls2 : 100 x 20 floats + 64-float wl2 scratch at [2000..2063] (8.26 KB).
__global__ __launch_bounds__(256, 2) void kf(const _Float16* __restrict__ s1g,
        const float* __restrict__ w2, const float* __restrict__ wp2,
        const float* __restrict__ lw, float* __restrict__ out) {
    __shared__ __align__(16) _Float16 ls1h[100 * 264];   // 52.8 KB
    __shared__ __align__(16) float    ls2[100 * 20 + 64];//  8.26 KB
    const int tid = threadIdx.x;
    const int bid = blockIdx.x;
    const int n   = (bid & 7) * 8 + (bid >> 6);   // XCD-aware, bijective
    const int oct = (bid >> 3) & 7;               // c2 channel
    const int wave = tid >> 6;
    const float a = DECAY;

    // --- stage: issue 13 coalesced float4 loads of the spike slice ---
    const float4* gs = (const float4*)(s1g + (size_t)n * 26400);  // 3300 float4
    float4 st[13];
    #pragma unroll
    for (int j = 0; j < 13; ++j) {
        const int idx = j * 256 + tid;
        if (idx < 3300) st[j] = gs[idx];
    }

    // --- fold wl2 (this block's channel) into ls2[2000..2063] (never overwritten) ---
    if (tid < 64) {
        const float p2 = wp2[0];
        const int cin = tid >> 4, e = (tid >> 2) & 3, f = tid & 3;
        int alo = e - 1; if (alo < 0) alo = 0;
        int ahi = e;     if (ahi > 2) ahi = 2;
        int blo = f - 1; if (blo < 0) blo = 0;
        int bhi = f;     if (bhi > 2) bhi = 2;
        float s = 0.f;
        for (int aa = alo; aa <= ahi; ++aa)
            for (int bb = blo; bb <= bhi; ++bb)
                s += w2[((oct * 4 + cin) * 3 + aa) * 3 + bb];
        ls2[2000 + cin * 16 + e * 4 + f] = s * p2;
    }

    // --- write staged spikes to LDS ---
    #pragma unroll
    for (int j = 0; j < 13; ++j) {
        const int idx = j * 256 + tid;
        if (idx < 3300) *(float4*)((char*)ls1h + idx * 16) = st[j];
    }
    BAR_LGKM();

    float4 wreg[16];   // [cin*4+e] = folded taps f0..3 for channel oct
    #pragma unroll
    for (int q = 0; q < 16; ++q)
        wreg[q] = *(const float4*)(ls2 + 2000 + (q >> 2) * 16 + (q & 3) * 4);

    // P2 mapping: thread = (sub, i2, jhp)
    const int sub = tid >> 3, l8 = tid & 7;
    const int i2 = l8 >> 1, jhp = l8 & 1;

    // --- P2: conv2 (1 channel), 4 predicated passes x 32 slots ---
    #pragma unroll 1
    for (int pass = 0; pass < 4; ++pass) {
        const int slot = sub + 32 * pass;
        if (slot < 100) {
            const _Float16* sb = ls1h + slot * 264;
            float acc0 = 0.f, acc1 = 0.f;
            #pragma unroll
            for (int cin = 0; cin < 4; ++cin) {
                #pragma unroll
                for (int e = 0; e < 4; ++e) {
                    const int ri = 2 * i2 + e - 1;            // input row, -1..8
                    const int rc = (ri < 0) ? 0 : (ri > 7 ? 7 : ri);
                    const bool rok = (ri >= 0) && (ri <= 7);
                    const half8 hv = *(const half8*)(sb + cin * 64 + rc * 8);
                    float rr8[8];
                    #pragma unroll
                    for (int m = 0; m < 8; ++m) rr8[m] = (float)hv[m];
                    float xr[6];
                    xr[0] = jhp ? rr8[3] : 0.0f;
                    xr[1] = jhp ? rr8[4] : rr8[0];
                    xr[2] = jhp ? rr8[5] : rr8[1];
                    xr[3] = jhp ? rr8[6] : rr8[2];
                    xr[4] = jhp ? rr8[7] : rr8[3];
                    xr[5] = jhp ? 0.0f   : rr8[4];
                    if (!rok) {
                        #pragma unroll
                        for (int m = 0; m < 6; ++m) xr[m] = 0.0f;
                    }
                    const float4 wf = wreg[cin * 4 + e];
                    acc0 += xr[0] * wf.x; acc0 += xr[1] * wf.y;
                    acc0 += xr[2] * wf.z; acc0 += xr[3] * wf.w;
                    acc1 += xr[2] * wf.x; acc1 += xr[3] * wf.y;
                    acc1 += xr[4] * wf.z; acc1 += xr[5] * wf.w;
                }
            }
            *(float2*)(ls2 + slot * 20 + i2 * 4 + 2 * jhp) =
                make_float2(acc0, acc1);
        }
    }
    BAR_LGKM();

    // --- scan2: wave0 lanes 0..15 (one per cell), register-resident ---
    if (wave == 0 && (tid & 63) < 16) {
        const int cell = tid & 63;
        float ub[100];
        #pragma unroll
        for (int k = 0; k < 100; ++k) ub[k] = ls2[k * 20 + cell];
        float psp2 = 0.f, rr2 = 0.f;
        #pragma unroll
        for (int k = 0; k < 100; ++k) {
            psp2 = a * psp2 + ub[k];
            const float vv = psp2 - rr2;
            const float s = (vv >= 1.f) ? 1.f : 0.f;
            rr2 = a * (rr2 + s);
            ls2[k * 20 + cell] = s;     // store-only publish
        }
    }
    BAR_LGKM();

    // --- dense: thread (t,o) dots 16 spikes x 16 weights ---
    if (tid < 200) {
        const int t = tid >> 1, o = tid & 1;
        const float* srow = ls2 + t * 20;
        const float* wrow = lw + o * 128 + oct * 16;
        const float4 s0 = *(const float4*)(srow);
        const float4 s1 = *(const float4*)(srow + 4);
        const float4 s2 = *(const float4*)(srow + 8);
        const float4 s3 = *(const float4*)(srow + 12);
        const float4 w0 = *(const float4*)(wrow);
        const float4 w1v = *(const float4*)(wrow + 4);
        const float4 w2v = *(const float4*)(wrow + 8);
        const float4 w3 = *(const float4*)(wrow + 12);
        float v = 0.f;
        v += s0.x * w0.x;  v += s0.y * w0.y;  v += s0.z * w0.z;  v += s0.w * w0.w;
        v += s1.x * w1v.x; v += s1.y * w1v.y; v += s1.z * w1v.z; v += s1.w * w1v.w;
        v += s2.x * w2v.x; v += s2.y * w2v.y; v += s2.z * w2v.z; v += s2.w * w2v.w;
        v += s3.x * w3.x;  v += s3.y * w3.y;  v += s3.z * w3.z;  v += s3.w * w3.w;
        atomicAdd(&out[n * 200 + t * 2 + o], v);
    }
}

extern "C" void kernel_launch(void* const* d_in, const int* in_sizes, int n_in,
                              void* d_out, int out_size, void* d_ws, size_t ws_size,
                              hipStream_t stream) {
    const float* x   = (const float*)d_in[0];
    const float* w1  = (const float*)d_in[1];
    const float* w2  = (const float*)d_in[2];
    const float* lw  = (const float*)d_in[3];
    const float* wp1 = (const float*)d_in[4];
    const float* wp2 = (const float*)d_in[5];

    float*     u1  = (float*)d_ws;              // [64][100][256] f32, 6.55 MB
    float*     wl1 = u1 + 1638400;              // 512 floats
    _Float16*  s1g = (_Float16*)(wl1 + 512);    // [64][100*264] f16, 3.38 MB
    float*     out = (float*)d_out;             // (64,100,2)

    k0_fold<<<4, 128, 0, stream>>>(w1, wp1, wl1);
    k1<<<6400, 64, 0, stream>>>(x, wl1, u1, out);
    k_s<<<64, 256, 0, stream>>>(u1, s1g);
    kf<<<512, 256, 0, stream>>>(s1g, w2, wp2, lw, out);
}

// Round 7
// 126.132 us; speedup vs baseline: 1.5387x; 1.0062x over previous
//
#include <hip/hip_runtime.h>

// SLAYER SNN forward, MI355X. Round 20.
// vs R19: k_s deleted (was a 4th launch + 6.6 MB s1g round-trip). kf does
//   scan1 inline again, but with a 10-deep ROLLING load pipeline (pb[10],
//   statically indexed via unroll-10): consume one u, refill one, publish
//   f16 spike to LDS immediately. Live state ~20 VGPRs (R13's vbuf[100] +
//   wreg[64] forced spills at VGPR=132 -- the original kf P1 pathology).
//   wreg is loaded from LDS scratch only AFTER the barrier, so it never
//   coexists with the load window. n-major u1 + XCD swizzle retained:
//   per block a contiguous 102.4 KB slice, 8 oct-siblings share one XCD L2.
// k0 (slim 4-block wl1 fold) and k1 (R9 core, n-major write, out-zeroing)
// unchanged from R19.

#define DECAY 0.9048374180359595f   // exp(-1/10)

#define BAR_LGKM() asm volatile("s_waitcnt lgkmcnt(0)\n\ts_barrier" ::: "memory")
#define FENCE_LGKM() asm volatile("s_waitcnt lgkmcnt(0)" ::: "memory")

typedef __attribute__((ext_vector_type(8))) _Float16 half8;

// ---------------- k0: fold wl1 (512 entries, 4 blocks x 128) ----------------
__global__ __launch_bounds__(128) void k0_fold(const float* __restrict__ w1,
        const float* __restrict__ wp1, float* __restrict__ wl1) {
    const int idx = blockIdx.x * 128 + threadIdx.x;   // 0..511
    const float p1 = wp1[0];
    const int f = idx & 7, c = (idx >> 3) & 3, e = (idx >> 5) & 7, cin = idx >> 8;
    const int cc = c * 2 + cin;
    int alo = e - 3; if (alo < 0) alo = 0;
    int ahi = e;     if (ahi > 4) ahi = 4;
    int blo = f - 3; if (blo < 0) blo = 0;
    int bhi = f;     if (bhi > 4) bhi = 4;
    float s = 0.f;
    for (int a = alo; a <= ahi; ++a)
        for (int b = blo; b <= bhi; ++b)
            s += w1[cc * 25 + a * 5 + b];
    wl1[(cin * 8 + e) * 32 + c * 8 + f] = s * p1;
}

// ---------------- k1: conv1+pool1 (R9 core) + out zero, n-major u1 ----------------
__global__ __launch_bounds__(64) void k1(const float* __restrict__ x,
        const float* __restrict__ wg, float* __restrict__ u1,
        float* __restrict__ out) {
    __shared__ __align__(16) float xs[2 * 1296];
    __shared__ __align__(16) float wl[512];
    const int lane = threadIdx.x;
    const int frame = blockIdx.x;                  // = n*100 + t (x is n-major)
    const int n = frame / 100, t = frame % 100;

    // zero out (blocks 0..49 cover 12800 floats)
    if (frame < 50) {
        #pragma unroll
        for (int q = 0; q < 4; ++q)
            out[frame * 256 + q * 64 + lane] = 0.f;
    }

    *(float4*)(wl + 4 * lane)       = *(const float4*)(wg + 4 * lane);
    *(float4*)(wl + 256 + 4 * lane) = *(const float4*)(wg + 256 + 4 * lane);

    #pragma unroll
    for (int m0 = 0; m0 < 128; m0 += 64) {
        const int m = m0 + lane;
        if (m < 72) {
            const int cin = m / 36, rem = m % 36;
            const int rr = rem / 9, q4 = rem % 9;
            const int pr = (rr == 0) ? 0 : (rr == 1) ? 9 : (rr == 2) ? 26 : 35;
            *(float4*)(xs + cin * 1296 + pr * 36 + q4 * 4) = make_float4(0.f, 0.f, 0.f, 0.f);
        }
    }
    #pragma unroll
    for (int m0 = 0; m0 < 192; m0 += 64) {
        const int m = m0 + lane;
        if (m < 144) {
            const int cin = m / 72, rem = m % 72;
            const int side = rem & 1, pr = rem >> 1;
            *(float2*)(xs + cin * 1296 + pr * 36 + side * 34) = make_float2(0.f, 0.f);
        }
    }
    const float4* xg = (const float4*)(x + (size_t)frame * 2048);
    #pragma unroll
    for (int q = 0; q < 8; ++q) {
        const int m = q * 64 + lane;
        const float4 v = xg[m];
        const int li = 4 * m;
        const int cin = li >> 10, row = (li >> 5) & 31, col = li & 31;
        const int r = row + 2;
        const int pr = (r & 3) * 9 + (r >> 2);
        float* d = xs + cin * 1296 + pr * 36 + col + 2;
        *(float2*)(d)     = make_float2(v.x, v.y);
        *(float2*)(d + 2) = make_float2(v.z, v.w);
    }
    FENCE_LGKM();

    const int cp = lane >> 5;
    const int i  = (lane >> 2) & 7;
    const int jh = (lane >> 1) & 1;
    const int eh = lane & 1;

    float acc[2][4] = {{0.f, 0.f, 0.f, 0.f}, {0.f, 0.f, 0.f, 0.f}};
    const float* tb = xs + (i + eh) * 36 + jh * 16;
    #pragma unroll
    for (int cin = 0; cin < 2; ++cin) {
        #pragma unroll
        for (int et = 0; et < 4; ++et) {
            const int ro = cin * 1296 + et * 9 * 36;
            float xr[20];
            #pragma unroll
            for (int b = 0; b < 5; ++b)
                *(float4*)(xr + 4 * b) = *(const float4*)(tb + ro + 4 * b);
            float wv[16];
            const float* wp = wl + (cin * 8 + eh * 4 + et) * 32 + cp * 16;
            #pragma unroll
            for (int q = 0; q < 4; ++q)
                *(float4*)(wv + 4 * q) = *(const float4*)(wp + 4 * q);
            #pragma unroll
            for (int cl = 0; cl < 2; ++cl) {
                #pragma unroll
                for (int jj = 0; jj < 4; ++jj) {
                    const int o = 4 * jj;
                    acc[cl][jj] += xr[o]*wv[cl*8]     + xr[o+1]*wv[cl*8+1]
                                 + xr[o+2]*wv[cl*8+2] + xr[o+3]*wv[cl*8+3]
                                 + xr[o+4]*wv[cl*8+4] + xr[o+5]*wv[cl*8+5]
                                 + xr[o+6]*wv[cl*8+6] + xr[o+7]*wv[cl*8+7];
                }
            }
        }
    }
    #pragma unroll
    for (int cl = 0; cl < 2; ++cl)
        #pragma unroll
        for (int jj = 0; jj < 4; ++jj)
            acc[cl][jj] += __shfl_xor(acc[cl][jj], 1);

    const float o0 = eh ? acc[1][0] : acc[0][0];
    const float o1 = eh ? acc[1][1] : acc[0][1];
    const float o2 = eh ? acc[1][2] : acc[0][2];
    const float o3 = eh ? acc[1][3] : acc[0][3];
    // n-major u1: [n][t][256]
    *(float4*)(u1 + (size_t)n * 25600 + t * 256 + (2 * cp + eh) * 64 + i * 8 + jh * 4) =
        make_float4(o0, o1, o2, o3);
}

// ---------------- kf: rolling scan1 + conv2(oct) + scan2 + dense ----------------
// grid 512 x 256: oct = (bid>>3)&7, n = (bid&7)*8 + (bid>>6)  (bijective;
// 8 oct siblings share bid%8 -> one XCD's L2 for the 102.4 KB u1 slice).
// P1 = 10-deep rolling pipeline: pb[10] prefetch window (static idx via
// unroll 10), consume 1 + refill 1 per step, publish f16 spike to ls1h.
// ls1h: 100 x 264 halfs (52.8 KB). ls2: 100 x 20 f32 + wl2 scratch at
// [2000..2063] (8.26 KB total). 2 blocks/CU.
__global__ __launch_bounds__(256, 2) void kf(const float* __restrict__ u1,
        const float* __restrict__ w2, const float* __restrict__ wp2,
        const float* __restrict__ lw, float* __restrict__ out) {
    __shared__ __align__(16) _Float16 ls1h[100 * 264];    // 52.8 KB
    __shared__ __align__(16) float    ls2[100 * 20 + 64]; //  8.26 KB
    const int tid = threadIdx.x;
    const int bid = blockIdx.x;
    const int n   = (bid & 7) * 8 + (bid >> 6);   // XCD-aware, bijective
    const int oct = (bid >> 3) & 7;               // c2 channel
    const int wave = tid >> 6;
    const float a = DECAY;

    // --- fold wl2 (this block's channel) into ls2[2000..2063] scratch ---
    if (tid < 64) {
        const float p2 = wp2[0];
        const int cin = tid >> 4, e = (tid >> 2) & 3, f = tid & 3;
        int alo = e - 1; if (alo < 0) alo = 0;
        int ahi = e;     if (ahi > 2) ahi = 2;
        int blo = f - 1; if (blo < 0) blo = 0;
        int bhi = f;     if (bhi > 2) bhi = 2;
        float s = 0.f;
        for (int aa = alo; aa <= ahi; ++aa)
            for (int bb = blo; bb <= bhi; ++bb)
                s += w2[((oct * 4 + cin) * 3 + aa) * 3 + bb];
        ls2[2000 + cin * 16 + e * 4 + f] = s * p2;
    }

    // --- P1: rolling scan1 (10-deep prefetch window, ~20 live VGPRs) ---
    {
        const float* up = u1 + (size_t)n * 25600 + tid;
        float pb[10];
        #pragma unroll
        for (int j = 0; j < 10; ++j) pb[j] = up[j * 256];
        float psp = 0.f, rr = 0.f;
        #pragma unroll 10
        for (int k = 0; k < 100; ++k) {
            const float cur = pb[k % 10];          // static after unroll-10
            if (k + 10 < 100) pb[k % 10] = up[(k + 10) * 256];
            psp = a * psp + cur;
            const float vv = psp - rr;
            const float s = (vv >= 1.f) ? 1.f : 0.f;
            rr = a * (rr + s);
            ls1h[k * 264 + tid] = (_Float16)s;     // 0/1 exact in f16
        }
    }
    BAR_LGKM();

    float4 wreg[16];   // [cin*4+e] = folded taps f0..3 for channel oct
    #pragma unroll
    for (int q = 0; q < 16; ++q)
        wreg[q] = *(const float4*)(ls2 + 2000 + (q >> 2) * 16 + (q & 3) * 4);

    // P2 mapping: thread = (sub, i2, jhp)
    const int sub = tid >> 3, l8 = tid & 7;
    const int i2 = l8 >> 1, jhp = l8 & 1;

    // --- P2: conv2 (1 channel), 4 predicated passes x 32 slots ---
    #pragma unroll 1
    for (int pass = 0; pass < 4; ++pass) {
        const int slot = sub + 32 * pass;
        if (slot < 100) {
            const _Float16* sb = ls1h + slot * 264;
            float acc0 = 0.f, acc1 = 0.f;
            #pragma unroll
            for (int cin = 0; cin < 4; ++cin) {
                #pragma unroll
                for (int e = 0; e < 4; ++e) {
                    const int ri = 2 * i2 + e - 1;            // input row, -1..8
                    const int rc = (ri < 0) ? 0 : (ri > 7 ? 7 : ri);
                    const bool rok = (ri >= 0) && (ri <= 7);
                    const half8 hv = *(const half8*)(sb + cin * 64 + rc * 8);
                    float rr8[8];
                    #pragma unroll
                    for (int m = 0; m < 8; ++m) rr8[m] = (float)hv[m];
                    float xr[6];
                    xr[0] = jhp ? rr8[3] : 0.0f;
                    xr[1] = jhp ? rr8[4] : rr8[0];
                    xr[2] = jhp ? rr8[5] : rr8[1];
                    xr[3] = jhp ? rr8[6] : rr8[2];
                    xr[4] = jhp ? rr8[7] : rr8[3];
                    xr[5] = jhp ? 0.0f   : rr8[4];
                    if (!rok) {
                        #pragma unroll
                        for (int m = 0; m < 6; ++m) xr[m] = 0.0f;
                    }
                    const float4 wf = wreg[cin * 4 + e];
                    acc0 += xr[0] * wf.x; acc0 += xr[1] * wf.y;
                    acc0 += xr[2] * wf.z; acc0 += xr[3] * wf.w;
                    acc1 += xr[2] * wf.x; acc1 += xr[3] * wf.y;
                    acc1 += xr[4] * wf.z; acc1 += xr[5] * wf.w;
                }
            }
            *(float2*)(ls2 + slot * 20 + i2 * 4 + 2 * jhp) =
                make_float2(acc0, acc1);
        }
    }
    BAR_LGKM();

    // --- scan2: wave0 lanes 0..15 (one per cell), register-resident ---
    if (wave == 0 && (tid & 63) < 16) {
        const int cell = tid & 63;
        float ub[100];
        #pragma unroll
        for (int k = 0; k < 100; ++k) ub[k] = ls2[k * 20 + cell];
        float psp2 = 0.f, rr2 = 0.f;
        #pragma unroll
        for (int k = 0; k < 100; ++k) {
            psp2 = a * psp2 + ub[k];
            const float vv = psp2 - rr2;
            const float s = (vv >= 1.f) ? 1.f : 0.f;
            rr2 = a * (rr2 + s);
            ls2[k * 20 + cell] = s;     // store-only publish
        }
    }
    BAR_LGKM();

    // --- dense: thread (t,o) dots 16 spikes x 16 weights ---
    if (tid < 200) {
        const int t = tid >> 1, o = tid & 1;
        const float* srow = ls2 + t * 20;
        const float* wrow = lw + o * 128 + oct * 16;
        const float4 s0 = *(const float4*)(srow);
        const float4 s1 = *(const float4*)(srow + 4);
        const float4 s2 = *(const float4*)(srow + 8);
        const float4 s3 = *(const float4*)(srow + 12);
        const float4 w0 = *(const float4*)(wrow);
        const float4 w1v = *(const float4*)(wrow + 4);
        const float4 w2v = *(const float4*)(wrow + 8);
        const float4 w3 = *(const float4*)(wrow + 12);
        float v = 0.f;
        v += s0.x * w0.x;  v += s0.y * w0.y;  v += s0.z * w0.z;  v += s0.w * w0.w;
        v += s1.x * w1v.x; v += s1.y * w1v.y; v += s1.z * w1v.z; v += s1.w * w1v.w;
        v += s2.x * w2v.x; v += s2.y * w2v.y; v += s2.z * w2v.z; v += s2.w * w2v.w;
        v += s3.x * w3.x;  v += s3.y * w3.y;  v += s3.z * w3.z;  v += s3.w * w3.w;
        atomicAdd(&out[n * 200 + t * 2 + o], v);
    }
}

extern "C" void kernel_launch(void* const* d_in, const int* in_sizes, int n_in,
                              void* d_out, int out_size, void* d_ws, size_t ws_size,
                              hipStream_t stream) {
    const float* x   = (const float*)d_in[0];
    const float* w1  = (const float*)d_in[1];
    const float* w2  = (const float*)d_in[2];
    const float* lw  = (const float*)d_in[3];
    const float* wp1 = (const float*)d_in[4];
    const float* wp2 = (const float*)d_in[5];

    float* u1  = (float*)d_ws;           // [64][100][256] f32, n-major, 6.55 MB
    float* wl1 = u1 + 1638400;           // 512 floats
    float* out = (float*)d_out;          // (64,100,2) = 12800 floats

    k0_fold<<<4, 128, 0, stream>>>(w1, wp1, wl1);
    k1<<<6400, 64, 0, stream>>>(x, wl1, u1, out);
    kf<<<512, 256, 0, stream>>>(u1, w2, wp2, lw, out);
}